// Round 17
// baseline (139.357 us; speedup 1.0000x reference)
//
#include <hip/hip_runtime.h>
#include <stdint.h>

#define NB    1024   // batch
#define NUM   512    // nodes
#define HD    64     // hidden dim
#define NE    4096   // edges
#define NEP   4608   // padded edge capacity (each column padded to even count)
#define MAIN  10     // softmax segment

typedef _Float16 hlf;
typedef __attribute__((ext_vector_type(2))) _Float16 hlf2;
typedef __attribute__((ext_vector_type(8))) _Float16 hlf8;
typedef __attribute__((ext_vector_type(4))) float f32x4;

__device__ __forceinline__ unsigned short f2h(float f) {
    hlf v = (hlf)f;
    return __builtin_bit_cast(unsigned short, v);
}

// ---------------------------------------------------------------------------
// Prep (identical to the proven R6/R14 kernel): block 0 builds degree-sorted,
// even-padded CSR via wave-shfl scans; blocks 1..72 cast E1 = emb@W1 and
// W2T = W2^T to f16. Edge pack: epk = (row << 23) | f16(norm).
// ---------------------------------------------------------------------------
__global__ __launch_bounds__(512) void prep_all(
    const int* __restrict__ erow, const int* __restrict__ ecol,
    const float* __restrict__ emb, const float* __restrict__ W1,
    const float* __restrict__ W2,
    int* __restrict__ rsptr, int* __restrict__ colmap, int* __restrict__ epk,
    short* __restrict__ E1, short* __restrict__ W2T)
{
    const int t = threadIdx.x;
    if (blockIdx.x != 0) {
        int g = (blockIdx.x - 1) * 512 + t;     // 72 x 512 = 36864
        if (g < NUM * HD) {
            int node = g >> 6, dim = g & 63;
            float acc = 0.0f;
            #pragma unroll
            for (int k = 0; k < HD; ++k) acc += emb[node * HD + k] * W1[k * HD + dim];
            E1[g] = (short)f2h(acc);
        } else if (g < NUM * HD + HD * HD) {
            int j = g - NUM * HD;
            int dout = j >> 6, din = j & 63;
            W2T[j] = (short)f2h(W2[din * HD + dout]);
        }
        return;
    }

    __shared__ int   sdeg[NUM];
    __shared__ int   aux[NUM];
    __shared__ float sdv[NUM];
    __shared__ int   rnk[NUM];
    __shared__ int   rdg[NUM];
    __shared__ int   wsum[8];

    const int lane = t & 63, wv = t >> 6;

    sdeg[t] = 0; aux[t] = 0;
    __syncthreads();
    for (int e = t; e < NE; e += 512) atomicAdd(&sdeg[ecol[e]], 1);
    __syncthreads();
    const int deg  = sdeg[t];
    const int pdeg = (deg + 1) & ~1;            // pad to even
    const int dbin = deg < NUM ? deg : NUM - 1;
    sdv[t] = deg > 0 ? rsqrtf((float)deg) : 0.0f;
    atomicAdd(&aux[dbin], 1);
    __syncthreads();
    {
        int v = aux[t];
        #pragma unroll
        for (int ofs = 1; ofs < 64; ofs <<= 1) {
            int sh = __shfl_up(v, ofs, 64);
            if (lane >= ofs) v += sh;
        }
        if (lane == 63) wsum[wv] = v;
        __syncthreads();
        if (t == 0) {
            int s = 0;
            #pragma unroll
            for (int w = 0; w < 8; ++w) { int tmp = wsum[w]; wsum[w] = s; s += tmp; }
        }
        __syncthreads();
        int inc = v + wsum[wv];
        aux[t]  = inc;
        __syncthreads();
        sdeg[t] = (t == 0) ? 0 : aux[t - 1];
        __syncthreads();
    }
    {
        int r = atomicAdd(&sdeg[dbin], 1);      // degree-sorted rank
        rnk[t] = r;
        rdg[r] = pdeg;
        colmap[r] = t;
    }
    __syncthreads();
    {
        int dv = rdg[t], v = dv;
        #pragma unroll
        for (int ofs = 1; ofs < 64; ofs <<= 1) {
            int sh = __shfl_up(v, ofs, 64);
            if (lane >= ofs) v += sh;
        }
        if (lane == 63) wsum[wv] = v;
        __syncthreads();
        if (t == 0) {
            int s = 0;
            #pragma unroll
            for (int w = 0; w < 8; ++w) { int tmp = wsum[w]; wsum[w] = s; s += tmp; }
        }
        __syncthreads();
        int inc  = v + wsum[wv];
        int excl = inc - dv;
        rsptr[t] = excl;
        if (t == NUM - 1) rsptr[NUM] = inc;
        aux[t] = excl;
        __syncthreads();
    }
    sdeg[t] = aux[rnk[t]];
    __syncthreads();
    for (int i = t; i < NEP; i += 512) epk[i] = 0;
    __syncthreads();
    for (int e = t; e < NE; e += 512) {
        int c = ecol[e], rr = erow[e];
        int p = atomicAdd(&sdeg[c], 1);
        unsigned ns = (unsigned)f2h(sdv[rr] * sdv[c]);
        epk[p] = (rr << 23) | (int)ns;          // hi16 = row*128 (byte offset)
    }
}

// ---------------------------------------------------------------------------
// Body: one block (1024 thr, 16 waves) per batch element; 2 blocks/CU
// (73.7 KB LDS, launch_bounds(1024,8), total regs <= 64). R16 structure +
// issue-overhead trims: 4-edge SpMM1 main loop, hoisted b1 strips,
// x staged through LDS (reusing tv) for the B1 build.
// ---------------------------------------------------------------------------
__global__ __launch_bounds__(1024, 8) void gcn_body(
    const float* __restrict__ x, const hlf* __restrict__ E1,
    const hlf* __restrict__ W2T,
    const float* __restrict__ b1, const float* __restrict__ b2,
    const float* __restrict__ W3, const float* __restrict__ b3,
    const int* __restrict__ rsptrg, const int* __restrict__ colmapg,
    const int* __restrict__ epkg,
    float* __restrict__ out)
{
    __shared__ hlf   H[NUM * HD];      // 65536 B, time-shared: B1 / h1 / g
    __shared__ int   sptr[513];
    __shared__ int   cmap[NUM];
    __shared__ float tv[NUM];          // x-stage (B1 build), then tv
    __shared__ float slog[NUM];
    __shared__ float sred[2];

    const int t     = threadIdx.x;
    const int b     = blockIdx.x;
    const int lane  = t & 63;
    const int wave  = t >> 6;          // 0..15
    const int q     = lane >> 4;
    const int l15   = lane & 15;
    const int gid   = t >> 3;          // 0..127: 8-lane group
    const int dbase = (lane & 7) * 8;  // this lane's 8-dim strip

    if (t < 513) sptr[t] = rsptrg[t];
    if (t < NUM) cmap[t] = colmapg[t];
    if (t < NUM) tv[t] = x[b * NUM + t];   // coalesced x stage
    __syncthreads();

    // ---- build H = B1: B1[r][d] = x[b,r] * E1[r][d]   (f16 storage)
    #pragma unroll
    for (int p = 0; p < 4; ++p) {
        int i = t + p * 1024;
        int r = i >> 3, d8 = (i & 7) * 8;
        hlf  xh = (hlf)tv[r];
        hlf8 e  = *(const hlf8*)&E1[r * HD + d8];
        hlf8 o;
        #pragma unroll
        for (int j = 0; j < 8; ++j) o[j] = e[j] * xh;
        *(hlf8*)&H[r * HD + d8] = o;
    }
    const char* Hb = (const char*)H + dbase * 2;   // per-lane gather base
    __syncthreads();

// v_fma_mix_f32: ACC += (f16 half of SRC) * (f16 low half of NRM)
#define FMIXL(ACC, SRC, NRM)                                                  \
    asm("v_fma_mix_f32 %0, %1, %2, %0 op_sel:[0,0,0] op_sel_hi:[1,1,0]"       \
        : "+v"(ACC) : "v"(SRC), "v"(NRM));
#define FMIXH(ACC, SRC, NRM)                                                  \
    asm("v_fma_mix_f32 %0, %1, %2, %0 op_sel:[1,0,0] op_sel_hi:[1,1,0]"       \
        : "+v"(ACC) : "v"(SRC), "v"(NRM));

#define MACROW(acc, hv, pe) {                                                 \
        FMIXL(acc[0], (hv).x, (pe)) FMIXH(acc[1], (hv).x, (pe))               \
        FMIXL(acc[2], (hv).y, (pe)) FMIXH(acc[3], (hv).y, (pe))               \
        FMIXL(acc[4], (hv).z, (pe)) FMIXH(acc[5], (hv).z, (pe))               \
        FMIXL(acc[6], (hv).w, (pe)) FMIXH(acc[7], (hv).w, (pe)) }

// hi16(pe) = row*128 = byte offset into 128B rows
#define LDROW(d, pe) d = *(const uint4*)(Hb + ((unsigned)(pe) >> 16));

// shared 4-edge + 2-edge gather loop into a[8]
#define GATHER_LOOP(E0, E1V) {                                                \
        int e = (E0);                                                         \
        for (; e + 4 <= (E1V); e += 4) {                                      \
            int2 qa = *(const int2*)&epkg[e];                                 \
            int2 qb = *(const int2*)&epkg[e + 2];                             \
            uint4 c0, c1, c2, c3;                                             \
            LDROW(c0, qa.x) LDROW(c1, qa.y) LDROW(c2, qb.x) LDROW(c3, qb.y)   \
            MACROW(a, c0, qa.x) MACROW(a, c1, qa.y)                           \
            MACROW(a, c2, qb.x) MACROW(a, c3, qb.y)                           \
        }                                                                     \
        if (e < (E1V)) {                                                      \
            int2 qa = *(const int2*)&epkg[e];                                 \
            uint4 c0, c1;                                                     \
            LDROW(c0, qa.x) LDROW(c1, qa.y)                                   \
            MACROW(a, c0, qa.x) MACROW(a, c1, qa.y)                           \
        }                                                                     }

// one SpMM1 rank: accumulate, bias+relu, pack into the named hold HV
#define SPMM1_SET(SET, HV) {                                                  \
        int r  = (SET) * 128 + gid;                                           \
        int e0 = sptr[r], e1 = sptr[r + 1];                                   \
        float a[8];                                                           \
        _Pragma("unroll")                                                     \
        for (int j = 0; j < 8; ++j) a[j] = 0.0f;                              \
        GATHER_LOOP(e0, e1)                                                   \
        HV.x = __builtin_bit_cast(unsigned, __builtin_amdgcn_cvt_pkrtz(       \
                   fmaxf(a[0] + bb0[0], 0.0f), fmaxf(a[1] + bb0[1], 0.0f)));  \
        HV.y = __builtin_bit_cast(unsigned, __builtin_amdgcn_cvt_pkrtz(       \
                   fmaxf(a[2] + bb0[2], 0.0f), fmaxf(a[3] + bb0[3], 0.0f)));  \
        HV.z = __builtin_bit_cast(unsigned, __builtin_amdgcn_cvt_pkrtz(       \
                   fmaxf(a[4] + bb1[0], 0.0f), fmaxf(a[5] + bb1[1], 0.0f)));  \
        HV.w = __builtin_bit_cast(unsigned, __builtin_amdgcn_cvt_pkrtz(       \
                   fmaxf(a[6] + bb1[2], 0.0f), fmaxf(a[7] + bb1[3], 0.0f)));  }

#define SPMM1_WB(SET, HV) {                                                   \
        int r = (SET) * 128 + gid;                                            \
        *(uint4*)&H[cmap[r] * HD + dbase] = HV;                               }

    // ---- SpMM1: h1 = relu(S@B1 + b1); 4 named holds, in-place write
    {
        const f32x4 bb0 = *(const f32x4*)&b1[dbase];
        const f32x4 bb1 = *(const f32x4*)&b1[dbase + 4];
        uint4 hv0, hv1, hv2, hv3;
        SPMM1_SET(0, hv0) SPMM1_SET(1, hv1) SPMM1_SET(2, hv2) SPMM1_SET(3, hv3)
        __syncthreads();   // all B1 gathers complete
        SPMM1_WB(0, hv0) SPMM1_WB(1, hv1) SPMM1_WB(2, hv2) SPMM1_WB(3, hv3)
    }
    __syncthreads();       // h1 complete

    // ---- MFMA: g = h1 @ W2, row-wise in place (wave-private rows, no holds)
    {
        #pragma unroll
        for (int mm = 0; mm < 2; ++mm) {
            int m = wave * 32 + mm * 16 + l15;
            hlf8 a0 = *(const hlf8*)&H[m * HD + q * 8];
            hlf8 a1 = *(const hlf8*)&H[m * HD + 32 + q * 8];
            uint2 gk0, gk1, gk2, gk3;
            #pragma unroll
            for (int nt = 0; nt < 4; ++nt) {
                hlf8 w0 = *(const hlf8*)&W2T[(nt * 16 + l15) * HD + q * 8];
                hlf8 w1 = *(const hlf8*)&W2T[(nt * 16 + l15) * HD + 32 + q * 8];
                f32x4 acc = (f32x4){0.f, 0.f, 0.f, 0.f};
                acc = __builtin_amdgcn_mfma_f32_16x16x32_f16(a0, w0, acc, 0, 0, 0);
                acc = __builtin_amdgcn_mfma_f32_16x16x32_f16(a1, w1, acc, 0, 0, 0);
                uint2 pk;
                pk.x = __builtin_bit_cast(unsigned,
                           __builtin_amdgcn_cvt_pkrtz(acc[0], acc[1]));
                pk.y = __builtin_bit_cast(unsigned,
                           __builtin_amdgcn_cvt_pkrtz(acc[2], acc[3]));
                if (nt == 0) gk0 = pk;
                else if (nt == 1) gk1 = pk;
                else if (nt == 2) gk2 = pk;
                else gk3 = pk;
            }
            int mrow = wave * 32 + mm * 16 + q * 4;
            #pragma unroll
            for (int nt = 0; nt < 4; ++nt) {
                uint2 pk = (nt == 0) ? gk0 : (nt == 1) ? gk1
                         : (nt == 2) ? gk2 : gk3;
                hlf2 lo = __builtin_bit_cast(hlf2, pk.x);
                hlf2 hi = __builtin_bit_cast(hlf2, pk.y);
                H[(mrow + 0) * HD + nt * 16 + l15] = lo[0];
                H[(mrow + 1) * HD + nt * 16 + l15] = lo[1];
                H[(mrow + 2) * HD + nt * 16 + l15] = hi[0];
                H[(mrow + 3) * HD + nt * 16 + l15] = hi[1];
            }
        }
    }
    __syncthreads();       // g complete

    // ---- SpMM2 + epilogue: tv[c] = sum_d relu((S@g)[c,d] + b2[d]) * W3[d]
    {
        const f32x4 v0 = *(const f32x4*)&b2[dbase];
        const f32x4 v1 = *(const f32x4*)&b2[dbase + 4];
        const f32x4 w0 = *(const f32x4*)&W3[dbase];
        const f32x4 w1 = *(const f32x4*)&W3[dbase + 4];
        #pragma unroll 1
        for (int set = 0; set < 4; ++set) {
            int r  = set * 128 + gid;
            int e0 = sptr[r], e1 = sptr[r + 1];
            int c  = cmap[r];
            float a[8];
            #pragma unroll
            for (int j = 0; j < 8; ++j) a[j] = 0.0f;
            GATHER_LOOP(e0, e1)
            float v = 0.0f;
            #pragma unroll
            for (int j = 0; j < 4; ++j) {
                v += fmaxf(a[j] + v0[j], 0.0f) * w0[j];
                v += fmaxf(a[j + 4] + v1[j], 0.0f) * w1[j];
            }
            v += __shfl_xor(v, 1, 64);
            v += __shfl_xor(v, 2, 64);
            v += __shfl_xor(v, 4, 64);
            if ((lane & 7) == 0) tv[c] = v;
        }
    }
    __syncthreads();

    // ---- SpMM3: slog[col] = (S @ tv)[col] + b3   (2 threads per rank)
    {
        int rk = t >> 1, hh = t & 1;
        int e0 = sptr[rk], e1 = sptr[rk + 1];
        int mid = (e0 + e1) >> 1;
        int ea = hh ? mid : e0;
        int eb = hh ? e1 : mid;
        float acc = 0.0f;
        for (int e = ea; e < eb; ++e) {
            unsigned pe = (unsigned)epkg[e];
            float nf = (float)__builtin_bit_cast(hlf2, pe)[0];
            acc = fmaf(nf, *(const float*)((const char*)tv + (pe >> 21)), acc);
        }
        acc += __shfl_xor(acc, 1, 64);
        if (!hh) slog[cmap[rk]] = acc + b3[0];
    }
    __syncthreads();

    // ---- softmax stats over [0, MAIN)
    if (t < 64) {
        float v = (t < MAIN) ? slog[t] : -1e30f;
        float m = v;
        m = fmaxf(m, __shfl_xor(m, 1, 64));
        m = fmaxf(m, __shfl_xor(m, 2, 64));
        m = fmaxf(m, __shfl_xor(m, 4, 64));
        m = fmaxf(m, __shfl_xor(m, 8, 64));
        float ev = (t < MAIN) ? __expf(v - m) : 0.0f;
        ev += __shfl_xor(ev, 1, 64);
        ev += __shfl_xor(ev, 2, 64);
        ev += __shfl_xor(ev, 4, 64);
        ev += __shfl_xor(ev, 8, 64);
        if (t == 0) { sred[0] = m; sred[1] = ev; }
    }
    __syncthreads();

    if (t < NUM) {
        float l = slog[t];
        float o = (t < MAIN) ? __expf(l - sred[0]) / sred[1]
                             : 1.0f / (1.0f + __expf(-l));
        out[b * NUM + t] = o;
    }
#undef MACROW
#undef LDROW
#undef FMIXL
#undef FMIXH
#undef GATHER_LOOP
#undef SPMM1_SET
#undef SPMM1_WB
}

// ---------------------------------------------------------------------------
extern "C" void kernel_launch(void* const* d_in, const int* in_sizes, int n_in,
                              void* d_out, int out_size, void* d_ws, size_t ws_size,
                              hipStream_t stream) {
    const float* x    = (const float*)d_in[0];
    const float* emb  = (const float*)d_in[1];
    const float* W1   = (const float*)d_in[2];
    const float* b1   = (const float*)d_in[3];
    const float* W2   = (const float*)d_in[4];
    const float* b2   = (const float*)d_in[5];
    const float* W3   = (const float*)d_in[6];
    const float* b3   = (const float*)d_in[7];
    const int*   erow = (const int*)d_in[8];
    const int*   ecol = (const int*)d_in[9];

    char* ws = (char*)d_ws;
    int*   rsptr  = (int*)ws;                // 513 ints  [0, 2052)
    int*   colmap = (int*)(ws + 2176);       // 512 ints  [2176, 4224)
    int*   epk    = (int*)(ws + 4224);       // 4608 ints [4224, 22656)
    short* E1     = (short*)(ws + 22656);    // 32768 f16 [22656, 88192)
    short* W2T    = (short*)(ws + 88192);    // 4096 f16  [88192, 96384)

    prep_all<<<73, 512, 0, stream>>>(erow, ecol, emb, W1, W2,
                                     rsptr, colmap, epk, E1, W2T);
    gcn_body<<<NB, 1024, 0, stream>>>(x, (const hlf*)E1, (const hlf*)W2T,
                                      b1, b2, W3, b3,
                                      rsptr, colmap, epk, (float*)d_out);
}

// Round 18
// 134.387 us; speedup vs baseline: 1.0370x; 1.0370x over previous
//
#include <hip/hip_runtime.h>
#include <stdint.h>

#define NB    1024   // batch
#define NUM   512    // nodes
#define HD    64     // hidden dim
#define NE    4096   // edges
#define NEP   4608   // padded edge capacity (each column padded to even count)
#define MAIN  10     // softmax segment

typedef _Float16 hlf;
typedef __attribute__((ext_vector_type(2))) _Float16 hlf2;
typedef __attribute__((ext_vector_type(8))) _Float16 hlf8;
typedef __attribute__((ext_vector_type(4))) float f32x4;

__device__ __forceinline__ unsigned short f2h(float f) {
    hlf v = (hlf)f;
    return __builtin_bit_cast(unsigned short, v);
}

// ---------------------------------------------------------------------------
// Prep (identical to the proven R6/R14 kernel): block 0 builds degree-sorted,
// even-padded CSR via wave-shfl scans; blocks 1..72 cast E1 = emb@W1 and
// W2T = W2^T to f16. Edge pack: epk = (row << 23) | f16(norm).
// ---------------------------------------------------------------------------
__global__ __launch_bounds__(512) void prep_all(
    const int* __restrict__ erow, const int* __restrict__ ecol,
    const float* __restrict__ emb, const float* __restrict__ W1,
    const float* __restrict__ W2,
    int* __restrict__ rsptr, int* __restrict__ colmap, int* __restrict__ epk,
    short* __restrict__ E1, short* __restrict__ W2T)
{
    const int t = threadIdx.x;
    if (blockIdx.x != 0) {
        int g = (blockIdx.x - 1) * 512 + t;     // 72 x 512 = 36864
        if (g < NUM * HD) {
            int node = g >> 6, dim = g & 63;
            float acc = 0.0f;
            #pragma unroll
            for (int k = 0; k < HD; ++k) acc += emb[node * HD + k] * W1[k * HD + dim];
            E1[g] = (short)f2h(acc);
        } else if (g < NUM * HD + HD * HD) {
            int j = g - NUM * HD;
            int dout = j >> 6, din = j & 63;
            W2T[j] = (short)f2h(W2[din * HD + dout]);
        }
        return;
    }

    __shared__ int   sdeg[NUM];
    __shared__ int   aux[NUM];
    __shared__ float sdv[NUM];
    __shared__ int   rnk[NUM];
    __shared__ int   rdg[NUM];
    __shared__ int   wsum[8];

    const int lane = t & 63, wv = t >> 6;

    sdeg[t] = 0; aux[t] = 0;
    __syncthreads();
    for (int e = t; e < NE; e += 512) atomicAdd(&sdeg[ecol[e]], 1);
    __syncthreads();
    const int deg  = sdeg[t];
    const int pdeg = (deg + 1) & ~1;            // pad to even
    const int dbin = deg < NUM ? deg : NUM - 1;
    sdv[t] = deg > 0 ? rsqrtf((float)deg) : 0.0f;
    atomicAdd(&aux[dbin], 1);
    __syncthreads();
    {
        int v = aux[t];
        #pragma unroll
        for (int ofs = 1; ofs < 64; ofs <<= 1) {
            int sh = __shfl_up(v, ofs, 64);
            if (lane >= ofs) v += sh;
        }
        if (lane == 63) wsum[wv] = v;
        __syncthreads();
        if (t == 0) {
            int s = 0;
            #pragma unroll
            for (int w = 0; w < 8; ++w) { int tmp = wsum[w]; wsum[w] = s; s += tmp; }
        }
        __syncthreads();
        int inc = v + wsum[wv];
        aux[t]  = inc;
        __syncthreads();
        sdeg[t] = (t == 0) ? 0 : aux[t - 1];
        __syncthreads();
    }
    {
        int r = atomicAdd(&sdeg[dbin], 1);      // degree-sorted rank
        rnk[t] = r;
        rdg[r] = pdeg;
        colmap[r] = t;
    }
    __syncthreads();
    {
        int dv = rdg[t], v = dv;
        #pragma unroll
        for (int ofs = 1; ofs < 64; ofs <<= 1) {
            int sh = __shfl_up(v, ofs, 64);
            if (lane >= ofs) v += sh;
        }
        if (lane == 63) wsum[wv] = v;
        __syncthreads();
        if (t == 0) {
            int s = 0;
            #pragma unroll
            for (int w = 0; w < 8; ++w) { int tmp = wsum[w]; wsum[w] = s; s += tmp; }
        }
        __syncthreads();
        int inc  = v + wsum[wv];
        int excl = inc - dv;
        rsptr[t] = excl;
        if (t == NUM - 1) rsptr[NUM] = inc;
        aux[t] = excl;
        __syncthreads();
    }
    sdeg[t] = aux[rnk[t]];
    __syncthreads();
    for (int i = t; i < NEP; i += 512) epk[i] = 0;
    __syncthreads();
    for (int e = t; e < NE; e += 512) {
        int c = ecol[e], rr = erow[e];
        int p = atomicAdd(&sdeg[c], 1);
        unsigned ns = (unsigned)f2h(sdv[rr] * sdv[c]);
        epk[p] = (rr << 23) | (int)ns;          // hi16 = row*128 (byte offset)
    }
}

// ---------------------------------------------------------------------------
// Body: one block (1024 thr, 16 waves) per batch element; 2 blocks/CU
// (73.7 KB LDS, launch_bounds(1024,8), total regs engineered <= 64):
//  - eps read from GLOBAL (18 KB, L1-hot, shared by co-resident blocks)
//  - SpMM1: 4 sets x 128 8-lane groups; only 4 named uint4 holds (16 regs)
//  - MFMA : g = h1@W2 is ROW-WISE -> each wave reads/writes only its own
//    32 rows: read-fragments -> MFMA -> write in place, NO holds, NO extra
//    barrier (cross-wave hazard impossible)
//  - SpMM2: 4-edge chunks, no holds
//  - all MACs are v_fma_mix_f32 (R15)
// NOTE (R17 lesson): do NOT hoist bias strips kernel-wide — at the 64-total
// register wall any extra live value spills the SpMM1 gather loop.
// ---------------------------------------------------------------------------
__global__ __launch_bounds__(1024, 8) void gcn_body(
    const float* __restrict__ x, const hlf* __restrict__ E1,
    const hlf* __restrict__ W2T,
    const float* __restrict__ b1, const float* __restrict__ b2,
    const float* __restrict__ W3, const float* __restrict__ b3,
    const int* __restrict__ rsptrg, const int* __restrict__ colmapg,
    const int* __restrict__ epkg,
    float* __restrict__ out)
{
    __shared__ hlf   H[NUM * HD];      // 65536 B, time-shared: B1 / h1 / g
    __shared__ int   sptr[513];
    __shared__ int   cmap[NUM];
    __shared__ float tv[NUM];
    __shared__ float slog[NUM];
    __shared__ float sred[2];

    const int t     = threadIdx.x;
    const int b     = blockIdx.x;
    const int lane  = t & 63;
    const int wave  = t >> 6;          // 0..15
    const int q     = lane >> 4;
    const int l15   = lane & 15;
    const int gid   = t >> 3;          // 0..127: 8-lane group
    const int dbase = (lane & 7) * 8;  // this lane's 8-dim strip

    if (t < 513) sptr[t] = rsptrg[t];
    if (t < NUM) cmap[t] = colmapg[t];

    // ---- build H = B1: B1[r][d] = x[b,r] * E1[r][d]   (f16 storage)
    #pragma unroll
    for (int p = 0; p < 4; ++p) {
        int i = t + p * 1024;
        int r = i >> 3, d8 = (i & 7) * 8;
        float xr = x[b * NUM + r];
        hlf  xh = (hlf)xr;
        hlf8 e  = *(const hlf8*)&E1[r * HD + d8];
        hlf8 o;
        #pragma unroll
        for (int j = 0; j < 8; ++j) o[j] = e[j] * xh;
        *(hlf8*)&H[r * HD + d8] = o;
    }
    const char* Hb = (const char*)H + dbase * 2;   // per-lane gather base
    __syncthreads();

// v_fma_mix_f32: ACC += (f16 half of SRC) * (f16 low half of NRM)
#define FMIXL(ACC, SRC, NRM)                                                  \
    asm("v_fma_mix_f32 %0, %1, %2, %0 op_sel:[0,0,0] op_sel_hi:[1,1,0]"       \
        : "+v"(ACC) : "v"(SRC), "v"(NRM));
#define FMIXH(ACC, SRC, NRM)                                                  \
    asm("v_fma_mix_f32 %0, %1, %2, %0 op_sel:[1,0,0] op_sel_hi:[1,1,0]"       \
        : "+v"(ACC) : "v"(SRC), "v"(NRM));

#define MACROW(acc, hv, pe) {                                                 \
        FMIXL(acc[0], (hv).x, (pe)) FMIXH(acc[1], (hv).x, (pe))               \
        FMIXL(acc[2], (hv).y, (pe)) FMIXH(acc[3], (hv).y, (pe))               \
        FMIXL(acc[4], (hv).z, (pe)) FMIXH(acc[5], (hv).z, (pe))               \
        FMIXL(acc[6], (hv).w, (pe)) FMIXH(acc[7], (hv).w, (pe)) }

// hi16(pe) = row*128 = byte offset into 128B rows
#define LDROW(d, pe) d = *(const uint4*)(Hb + ((unsigned)(pe) >> 16));

// one SpMM1 rank: accumulate, bias+relu, pack into the named hold HV
#define SPMM1_SET(SET, HV) {                                                  \
        int r  = (SET) * 128 + gid;                                           \
        int e0 = sptr[r], e1 = sptr[r + 1];                                   \
        float a[8];                                                           \
        _Pragma("unroll")                                                     \
        for (int j = 0; j < 8; ++j) a[j] = 0.0f;                              \
        for (int e = e0; e < e1; e += 2) {                                    \
            int2 qa = *(const int2*)&epkg[e];                                 \
            uint4 c0, c1;                                                     \
            LDROW(c0, qa.x) LDROW(c1, qa.y)                                   \
            MACROW(a, c0, qa.x) MACROW(a, c1, qa.y)                           \
        }                                                                     \
        f32x4 u0 = *(const f32x4*)&b1[dbase];                                 \
        f32x4 u1 = *(const f32x4*)&b1[dbase + 4];                             \
        HV.x = __builtin_bit_cast(unsigned, __builtin_amdgcn_cvt_pkrtz(       \
                   fmaxf(a[0] + u0[0], 0.0f), fmaxf(a[1] + u0[1], 0.0f)));    \
        HV.y = __builtin_bit_cast(unsigned, __builtin_amdgcn_cvt_pkrtz(       \
                   fmaxf(a[2] + u0[2], 0.0f), fmaxf(a[3] + u0[3], 0.0f)));    \
        HV.z = __builtin_bit_cast(unsigned, __builtin_amdgcn_cvt_pkrtz(       \
                   fmaxf(a[4] + u1[0], 0.0f), fmaxf(a[5] + u1[1], 0.0f)));    \
        HV.w = __builtin_bit_cast(unsigned, __builtin_amdgcn_cvt_pkrtz(       \
                   fmaxf(a[6] + u1[2], 0.0f), fmaxf(a[7] + u1[3], 0.0f)));    }

#define SPMM1_WB(SET, HV) {                                                   \
        int r = (SET) * 128 + gid;                                            \
        *(uint4*)&H[cmap[r] * HD + dbase] = HV;                               }

    // ---- SpMM1: h1 = relu(S@B1 + b1); 4 named holds, in-place write
    {
        uint4 hv0, hv1, hv2, hv3;
        SPMM1_SET(0, hv0) SPMM1_SET(1, hv1) SPMM1_SET(2, hv2) SPMM1_SET(3, hv3)
        __syncthreads();   // all B1 gathers complete
        SPMM1_WB(0, hv0) SPMM1_WB(1, hv1) SPMM1_WB(2, hv2) SPMM1_WB(3, hv3)
    }
    __syncthreads();       // h1 complete

    // ---- MFMA: g = h1 @ W2, row-wise in place (wave-private rows, no holds)
    {
        #pragma unroll
        for (int mm = 0; mm < 2; ++mm) {
            int m = wave * 32 + mm * 16 + l15;
            hlf8 a0 = *(const hlf8*)&H[m * HD + q * 8];
            hlf8 a1 = *(const hlf8*)&H[m * HD + 32 + q * 8];
            uint2 gk0, gk1, gk2, gk3;
            #pragma unroll
            for (int nt = 0; nt < 4; ++nt) {
                hlf8 w0 = *(const hlf8*)&W2T[(nt * 16 + l15) * HD + q * 8];
                hlf8 w1 = *(const hlf8*)&W2T[(nt * 16 + l15) * HD + 32 + q * 8];
                f32x4 acc = (f32x4){0.f, 0.f, 0.f, 0.f};
                acc = __builtin_amdgcn_mfma_f32_16x16x32_f16(a0, w0, acc, 0, 0, 0);
                acc = __builtin_amdgcn_mfma_f32_16x16x32_f16(a1, w1, acc, 0, 0, 0);
                uint2 pk;
                pk.x = __builtin_bit_cast(unsigned,
                           __builtin_amdgcn_cvt_pkrtz(acc[0], acc[1]));
                pk.y = __builtin_bit_cast(unsigned,
                           __builtin_amdgcn_cvt_pkrtz(acc[2], acc[3]));
                if (nt == 0) gk0 = pk;
                else if (nt == 1) gk1 = pk;
                else if (nt == 2) gk2 = pk;
                else gk3 = pk;
            }
            // write this 16-row tile (reads of it are complete; rows are
            // wave-private so no block barrier needed)
            int mrow = wave * 32 + mm * 16 + q * 4;
            #pragma unroll
            for (int nt = 0; nt < 4; ++nt) {
                uint2 pk = (nt == 0) ? gk0 : (nt == 1) ? gk1
                         : (nt == 2) ? gk2 : gk3;
                hlf2 lo = __builtin_bit_cast(hlf2, pk.x);
                hlf2 hi = __builtin_bit_cast(hlf2, pk.y);
                H[(mrow + 0) * HD + nt * 16 + l15] = lo[0];
                H[(mrow + 1) * HD + nt * 16 + l15] = lo[1];
                H[(mrow + 2) * HD + nt * 16 + l15] = hi[0];
                H[(mrow + 3) * HD + nt * 16 + l15] = hi[1];
            }
        }
    }
    __syncthreads();       // g complete

    // ---- SpMM2 + epilogue: tv[c] = sum_d relu((S@g)[c,d] + b2[d]) * W3[d]
    #pragma unroll 1
    for (int set = 0; set < 4; ++set) {
        int r  = set * 128 + gid;
        int e0 = sptr[r], e1 = sptr[r + 1];
        int c  = cmap[r];
        float a[8];
        #pragma unroll
        for (int j = 0; j < 8; ++j) a[j] = 0.0f;
        int e = e0;
        for (; e + 4 <= e1; e += 4) {
            int2 qa = *(const int2*)&epkg[e];
            int2 qb = *(const int2*)&epkg[e + 2];
            uint4 c0, c1, c2, c3;
            LDROW(c0, qa.x) LDROW(c1, qa.y) LDROW(c2, qb.x) LDROW(c3, qb.y)
            MACROW(a, c0, qa.x) MACROW(a, c1, qa.y)
            MACROW(a, c2, qb.x) MACROW(a, c3, qb.y)
        }
        if (e < e1) {
            int2 qa = *(const int2*)&epkg[e];
            uint4 c0, c1;
            LDROW(c0, qa.x) LDROW(c1, qa.y)
            MACROW(a, c0, qa.x) MACROW(a, c1, qa.y)
        }
        f32x4 v0 = *(const f32x4*)&b2[dbase], v1 = *(const f32x4*)&b2[dbase + 4];
        f32x4 w0 = *(const f32x4*)&W3[dbase], w1 = *(const f32x4*)&W3[dbase + 4];
        float v = 0.0f;
        #pragma unroll
        for (int j = 0; j < 4; ++j) {
            v += fmaxf(a[j] + v0[j], 0.0f) * w0[j];
            v += fmaxf(a[j + 4] + v1[j], 0.0f) * w1[j];
        }
        v += __shfl_xor(v, 1, 64);
        v += __shfl_xor(v, 2, 64);
        v += __shfl_xor(v, 4, 64);
        if ((lane & 7) == 0) tv[c] = v;
    }
    __syncthreads();

    // ---- SpMM3: slog[col] = (S @ tv)[col] + b3   (2 threads per rank)
    {
        int rk = t >> 1, hh = t & 1;
        int e0 = sptr[rk], e1 = sptr[rk + 1];
        int mid = (e0 + e1) >> 1;
        int ea = hh ? mid : e0;
        int eb = hh ? e1 : mid;
        float acc = 0.0f;
        for (int e = ea; e < eb; ++e) {
            unsigned pe = (unsigned)epkg[e];
            float nf = (float)__builtin_bit_cast(hlf2, pe)[0];
            acc = fmaf(nf, *(const float*)((const char*)tv + (pe >> 21)), acc);
        }
        acc += __shfl_xor(acc, 1, 64);
        if (!hh) slog[cmap[rk]] = acc + b3[0];
    }
    __syncthreads();

    // ---- softmax stats over [0, MAIN)
    if (t < 64) {
        float v = (t < MAIN) ? slog[t] : -1e30f;
        float m = v;
        m = fmaxf(m, __shfl_xor(m, 1, 64));
        m = fmaxf(m, __shfl_xor(m, 2, 64));
        m = fmaxf(m, __shfl_xor(m, 4, 64));
        m = fmaxf(m, __shfl_xor(m, 8, 64));
        float ev = (t < MAIN) ? __expf(v - m) : 0.0f;
        ev += __shfl_xor(ev, 1, 64);
        ev += __shfl_xor(ev, 2, 64);
        ev += __shfl_xor(ev, 4, 64);
        ev += __shfl_xor(ev, 8, 64);
        if (t == 0) { sred[0] = m; sred[1] = ev; }
    }
    __syncthreads();

    if (t < NUM) {
        float l = slog[t];
        float o = (t < MAIN) ? __expf(l - sred[0]) / sred[1]
                             : 1.0f / (1.0f + __expf(-l));
        out[b * NUM + t] = o;
    }
#undef MACROW
#undef LDROW
#undef FMIXL
#undef FMIXH
#undef SPMM1_SET
#undef SPMM1_WB
}

// ---------------------------------------------------------------------------
extern "C" void kernel_launch(void* const* d_in, const int* in_sizes, int n_in,
                              void* d_out, int out_size, void* d_ws, size_t ws_size,
                              hipStream_t stream) {
    const float* x    = (const float*)d_in[0];
    const float* emb  = (const float*)d_in[1];
    const float* W1   = (const float*)d_in[2];
    const float* b1   = (const float*)d_in[3];
    const float* W2   = (const float*)d_in[4];
    const float* b2   = (const float*)d_in[5];
    const float* W3   = (const float*)d_in[6];
    const float* b3   = (const float*)d_in[7];
    const int*   erow = (const int*)d_in[8];
    const int*   ecol = (const int*)d_in[9];

    char* ws = (char*)d_ws;
    int*   rsptr  = (int*)ws;                // 513 ints  [0, 2052)
    int*   colmap = (int*)(ws + 2176);       // 512 ints  [2176, 4224)
    int*   epk    = (int*)(ws + 4224);       // 4608 ints [4224, 22656)
    short* E1     = (short*)(ws + 22656);    // 32768 f16 [22656, 88192)
    short* W2T    = (short*)(ws + 88192);    // 4096 f16  [88192, 96384)

    prep_all<<<73, 512, 0, stream>>>(erow, ecol, emb, W1, W2,
                                     rsptr, colmap, epk, E1, W2T);
    gcn_body<<<NB, 1024, 0, stream>>>(x, (const hlf*)E1, (const hlf*)W2T,
                                      b1, b2, W3, b3,
                                      rsptr, colmap, epk, (float*)d_out);
}